// Round 13
// baseline (655.917 us; speedup 1.0000x reference)
//
#include <hip/hip_runtime.h>
#include <hip/hip_bf16.h>

#define NN 100000
#define EE 1600000
#define BSZ 512    // dst-nodes per coarse bucket
#define NBKT 196   // ceil(NN/BSZ)
#define CHUNK 8192 // edges per coarse chunk
#define NCH 196    // ceil(EE/CHUNK)

typedef short bf16x8 __attribute__((ext_vector_type(8)));
typedef float f32x4 __attribute__((ext_vector_type(4)));

// ---------------- bf16 helpers ----------------
__device__ inline unsigned short bf16_of(float f) {
    __hip_bfloat16 h = __float2bfloat16(f);   // RNE
    return *reinterpret_cast<unsigned short*>(&h);
}
__device__ inline unsigned pack2(float a, float b) {
    return (unsigned)bf16_of(a) | ((unsigned)bf16_of(b) << 16);
}
__device__ inline float bflo(unsigned u) { return __uint_as_float(u << 16); }
__device__ inline float bfhi(unsigned u) { return __uint_as_float(u & 0xffff0000u); }

// ---------------- CSR build ----------------

__global__ __launch_bounds__(256)
void k_ccount(const int* __restrict__ ei, int* __restrict__ ccount) {
    __shared__ int hist[NBKT];
    int tid = threadIdx.x;
    int e0 = blockIdx.x * CHUNK;
    int e1 = e0 + CHUNK; if (e1 > EE) e1 = EE;
    for (int i = tid; i < NBKT; i += 256) hist[i] = 0;
    __syncthreads();
    for (int e = e0 + tid; e < e1; e += 256)
        atomicAdd(&hist[ei[EE + e] >> 9], 1);
    __syncthreads();
    for (int i = tid; i < NBKT; i += 256)
        if (hist[i]) atomicAdd(&ccount[i], hist[i]);
}

__global__ void k_cscan(const int* __restrict__ ccount, int* __restrict__ cbase,
                        int* __restrict__ gcur) {
    __shared__ int s[256];
    int tid = threadIdx.x;
    int v = (tid < NBKT) ? ccount[tid] : 0;
    s[tid] = v;
    __syncthreads();
    for (int off = 1; off < 256; off <<= 1) {
        int t = (tid >= off) ? s[tid - off] : 0;
        __syncthreads();
        if (tid >= off) s[tid] += t;
        __syncthreads();
    }
    if (tid < NBKT) {
        int excl = s[tid] - v;
        cbase[tid] = excl;
        gcur[tid] = excl;
    }
    if (tid == NBKT - 1) cbase[NBKT] = s[tid];
}

// pairs packed: (src << 9) | (dst & 511)
__global__ __launch_bounds__(256)
void k_coarse(const int* __restrict__ ei, int* __restrict__ gcur, int* __restrict__ pairs) {
    __shared__ int hist[NBKT];
    __shared__ int base[NBKT];
    __shared__ int curs[NBKT];
    int tid = threadIdx.x;
    int e0 = blockIdx.x * CHUNK;
    int e1 = e0 + CHUNK; if (e1 > EE) e1 = EE;
    for (int i = tid; i < NBKT; i += 256) hist[i] = 0;
    __syncthreads();
    for (int e = e0 + tid; e < e1; e += 256)
        atomicAdd(&hist[ei[EE + e] >> 9], 1);
    __syncthreads();
    for (int i = tid; i < NBKT; i += 256) {
        base[i] = atomicAdd(&gcur[i], hist[i]);
        curs[i] = 0;
    }
    __syncthreads();
    for (int e = e0 + tid; e < e1; e += 256) {
        int src = ei[e];
        int dst = ei[EE + e];
        int b = dst >> 9;
        int off = atomicAdd(&curs[b], 1);
        pairs[base[b] + off] = (src << 9) | (dst & 511);
    }
}

__global__ __launch_bounds__(512)
void k_fine(const int* __restrict__ cbase, const int* __restrict__ pairs,
            int* __restrict__ rs, int* __restrict__ esrc) {
    __shared__ int deg[BSZ];
    __shared__ int s[BSZ];
    int b = blockIdx.x;
    int n0 = b * BSZ;
    int nlocal = NN - n0; if (nlocal > BSZ) nlocal = BSZ;
    int tid = threadIdx.x;
    deg[tid] = 0;
    __syncthreads();
    int e0 = cbase[b], e1 = cbase[b + 1];
    for (int e = e0 + tid; e < e1; e += 512)
        atomicAdd(&deg[pairs[e] & 511], 1);
    __syncthreads();
    int v = deg[tid];
    s[tid] = v;
    __syncthreads();
    for (int off = 1; off < 512; off <<= 1) {
        int t = (tid >= off) ? s[tid - off] : 0;
        __syncthreads();
        if (tid >= off) s[tid] += t;
        __syncthreads();
    }
    int excl = s[tid] - v;
    if (tid < nlocal) rs[n0 + tid] = e0 + excl;
    if (b == NBKT - 1 && tid == 0) rs[NN] = EE;
    deg[tid] = e0 + excl;
    __syncthreads();
    for (int e = e0 + tid; e < e1; e += 512) {
        int pk = pairs[e];
        int pos = atomicAdd(&deg[pk & 511], 1);
        esrc[pos] = pk >> 9;
    }
}

// ---------------- fused: x->bf16 + W packing + scratch zeroing ----------------
__global__ __launch_bounds__(256)
void k_tobfW(const float4* __restrict__ src, ushort4* __restrict__ dst,
             const float* __restrict__ Wl1, const float* __restrict__ Wr1,
             const float* __restrict__ Wl2, const float* __restrict__ Wr2,
             unsigned short* __restrict__ w1, unsigned short* __restrict__ w2,
             int* __restrict__ ccount, float* __restrict__ p64a,
             float* __restrict__ p64b, int* __restrict__ counters) {
    int b = blockIdx.x, tid = threadIdx.x;
    if (b < 6250) {
        int i = b * 256 + tid;
        if (i < NN * 16) {
            float4 v = src[i];
            dst[i] = make_ushort4(bf16_of(v.x), bf16_of(v.y), bf16_of(v.z), bf16_of(v.w));
        }
    } else {
        for (int i = tid; i < 8192; i += 256) {
            int n = i >> 7, k = i & 127;
            float v1 = (k < 64) ? Wl1[n * 64 + k] : Wr1[n * 64 + (k - 64)];
            w1[i] = bf16_of(v1);
            float v2 = (k < 64) ? Wl2[n * 64 + k] : Wr2[n * 64 + (k - 64)];
            w2[i] = bf16_of(v2);
            p64a[i] = 0.f;
            p64b[i] = 0.f;
        }
        if (tid < NBKT) ccount[tid] = 0;
        if (tid < 2) counters[tid] = 0;
    }
}

// ---------------- aggregation (64-dim) over bf16 table -> bf16 mean ----------------
__global__ __launch_bounds__(256, 8)
void k_aggbf(const unsigned short* __restrict__ xbf, const int* __restrict__ rs,
             const int* __restrict__ esrc, unsigned short* __restrict__ meanbf,
             const float* __restrict__ sc, const float* __restrict__ sh) {
    int gid = blockIdx.x * 256 + threadIdx.x;
    int node = gid >> 6;
    if (node >= NN) return;
    int lane = threadIdx.x & 63;
    int c = lane & 7;         // feature octet
    int slot = lane >> 3;     // neighbor slot 0..7
    int s0 = rs[node], s1 = rs[node + 1];
    const uint4* xb = (const uint4*)xbf;
    float a0 = 0.f, a1 = 0.f, a2 = 0.f, a3 = 0.f, a4 = 0.f, a5 = 0.f, a6 = 0.f, a7 = 0.f;
    if (sc) {
        float4 scl = ((const float4*)sc)[2 * c], sch = ((const float4*)sc)[2 * c + 1];
        float4 shl = ((const float4*)sh)[2 * c], shh = ((const float4*)sh)[2 * c + 1];
        int p = s0 + slot;
        for (; p + 8 < s1; p += 16) {
            uint4 va = xb[esrc[p] * 8 + c];
            uint4 vb = xb[esrc[p + 8] * 8 + c];
            a0 += fmaxf(fmaf(bflo(va.x), scl.x, shl.x), 0.f);
            a1 += fmaxf(fmaf(bfhi(va.x), scl.y, shl.y), 0.f);
            a2 += fmaxf(fmaf(bflo(va.y), scl.z, shl.z), 0.f);
            a3 += fmaxf(fmaf(bfhi(va.y), scl.w, shl.w), 0.f);
            a4 += fmaxf(fmaf(bflo(va.z), sch.x, shh.x), 0.f);
            a5 += fmaxf(fmaf(bfhi(va.z), sch.y, shh.y), 0.f);
            a6 += fmaxf(fmaf(bflo(va.w), sch.z, shh.z), 0.f);
            a7 += fmaxf(fmaf(bfhi(va.w), sch.w, shh.w), 0.f);
            a0 += fmaxf(fmaf(bflo(vb.x), scl.x, shl.x), 0.f);
            a1 += fmaxf(fmaf(bfhi(vb.x), scl.y, shl.y), 0.f);
            a2 += fmaxf(fmaf(bflo(vb.y), scl.z, shl.z), 0.f);
            a3 += fmaxf(fmaf(bfhi(vb.y), scl.w, shl.w), 0.f);
            a4 += fmaxf(fmaf(bflo(vb.z), sch.x, shh.x), 0.f);
            a5 += fmaxf(fmaf(bfhi(vb.z), sch.y, shh.y), 0.f);
            a6 += fmaxf(fmaf(bflo(vb.w), sch.z, shh.z), 0.f);
            a7 += fmaxf(fmaf(bfhi(vb.w), sch.w, shh.w), 0.f);
        }
        if (p < s1) {
            uint4 va = xb[esrc[p] * 8 + c];
            a0 += fmaxf(fmaf(bflo(va.x), scl.x, shl.x), 0.f);
            a1 += fmaxf(fmaf(bfhi(va.x), scl.y, shl.y), 0.f);
            a2 += fmaxf(fmaf(bflo(va.y), scl.z, shl.z), 0.f);
            a3 += fmaxf(fmaf(bfhi(va.y), scl.w, shl.w), 0.f);
            a4 += fmaxf(fmaf(bflo(va.z), sch.x, shh.x), 0.f);
            a5 += fmaxf(fmaf(bfhi(va.z), sch.y, shh.y), 0.f);
            a6 += fmaxf(fmaf(bflo(va.w), sch.z, shh.z), 0.f);
            a7 += fmaxf(fmaf(bfhi(va.w), sch.w, shh.w), 0.f);
        }
    } else {
        int p = s0 + slot;
        for (; p + 8 < s1; p += 16) {
            uint4 va = xb[esrc[p] * 8 + c];
            uint4 vb = xb[esrc[p + 8] * 8 + c];
            a0 += bflo(va.x) + bflo(vb.x); a1 += bfhi(va.x) + bfhi(vb.x);
            a2 += bflo(va.y) + bflo(vb.y); a3 += bfhi(va.y) + bfhi(vb.y);
            a4 += bflo(va.z) + bflo(vb.z); a5 += bfhi(va.z) + bfhi(vb.z);
            a6 += bflo(va.w) + bflo(vb.w); a7 += bfhi(va.w) + bfhi(vb.w);
        }
        if (p < s1) {
            uint4 va = xb[esrc[p] * 8 + c];
            a0 += bflo(va.x); a1 += bfhi(va.x);
            a2 += bflo(va.y); a3 += bfhi(va.y);
            a4 += bflo(va.z); a5 += bfhi(va.z);
            a6 += bflo(va.w); a7 += bfhi(va.w);
        }
    }
#pragma unroll
    for (int m = 8; m <= 32; m <<= 1) {
        a0 += __shfl_xor(a0, m, 64); a1 += __shfl_xor(a1, m, 64);
        a2 += __shfl_xor(a2, m, 64); a3 += __shfl_xor(a3, m, 64);
        a4 += __shfl_xor(a4, m, 64); a5 += __shfl_xor(a5, m, 64);
        a6 += __shfl_xor(a6, m, 64); a7 += __shfl_xor(a7, m, 64);
    }
    if (slot == 0) {
        int cnt = s1 - s0; if (cnt < 1) cnt = 1;
        float inv = 1.0f / (float)cnt;
        uint4 o;
        o.x = pack2(a0 * inv, a1 * inv);
        o.y = pack2(a2 * inv, a3 * inv);
        o.z = pack2(a4 * inv, a5 * inv);
        o.w = pack2(a6 * inv, a7 * inv);
        ((uint4*)meanbf)[node * 8 + c] = o;
    }
}

// ---------------- SAGE layer: LDS-free bf16 MFMA GEMM + fused BN-stat reduction ----------------
// BN stats: LDS partials -> atomicAdd into 64 slot-groups (32KB, ~24 RMW/line)
// -> fence+counter last-block pattern reduces and writes scale/shift inline.
__global__ __launch_bounds__(256, 4)
void k_sagemfma(const unsigned short* __restrict__ meanbf,  // (N,64) bf16
                const unsigned short* __restrict__ a2bf,    // (N,64) bf16
                const unsigned short* __restrict__ Wbf,     // (64,128) bf16 packed
                const float* __restrict__ bias,
                unsigned short* __restrict__ outbf,         // (N,64) bf16
                float* __restrict__ p64,                    // (64,128) slot-groups, pre-zeroed
                int* __restrict__ counter,                  // pre-zeroed
                const float* __restrict__ g, const float* __restrict__ be,
                float* __restrict__ scale, float* __restrict__ shift,
                const float* __restrict__ sc, const float* __restrict__ sh) {
    __shared__ float sblk[64];
    __shared__ float qblk[64];
    __shared__ float red2[256];
    __shared__ float fin[128];
    __shared__ int lastflag;
    const int tid = threadIdx.x;
    const int base = blockIdx.x * 64;
    const int col = tid & 15;
    const int q   = (tid >> 4) & 3;
    const int w   = tid >> 6;

    if (tid < 64) { sblk[tid] = 0.f; qblk[tid] = 0.f; }

    int gn = base + w * 16 + col; if (gn > NN - 1) gn = NN - 1;
    const uint4* mb = (const uint4*)meanbf;
    const uint4* ab = (const uint4*)a2bf;
    const uint4* wb = (const uint4*)Wbf;

    uint4 fa0 = mb[gn * 8 + q];
    uint4 fa1 = mb[gn * 8 + 4 + q];
    uint4 fa2 = ab[gn * 8 + q];
    uint4 fa3 = ab[gn * 8 + 4 + q];
    if (sc) {
        float4 s0 = ((const float4*)sc)[q * 2],     s1 = ((const float4*)sc)[q * 2 + 1];
        float4 h0 = ((const float4*)sh)[q * 2],     h1 = ((const float4*)sh)[q * 2 + 1];
        float4 s2 = ((const float4*)sc)[8 + q * 2], s3 = ((const float4*)sc)[8 + q * 2 + 1];
        float4 h2 = ((const float4*)sh)[8 + q * 2], h3 = ((const float4*)sh)[8 + q * 2 + 1];
        fa2.x = pack2(fmaxf(fmaf(bflo(fa2.x), s0.x, h0.x), 0.f),
                      fmaxf(fmaf(bfhi(fa2.x), s0.y, h0.y), 0.f));
        fa2.y = pack2(fmaxf(fmaf(bflo(fa2.y), s0.z, h0.z), 0.f),
                      fmaxf(fmaf(bfhi(fa2.y), s0.w, h0.w), 0.f));
        fa2.z = pack2(fmaxf(fmaf(bflo(fa2.z), s1.x, h1.x), 0.f),
                      fmaxf(fmaf(bfhi(fa2.z), s1.y, h1.y), 0.f));
        fa2.w = pack2(fmaxf(fmaf(bflo(fa2.w), s1.z, h1.z), 0.f),
                      fmaxf(fmaf(bfhi(fa2.w), s1.w, h1.w), 0.f));
        fa3.x = pack2(fmaxf(fmaf(bflo(fa3.x), s2.x, h2.x), 0.f),
                      fmaxf(fmaf(bfhi(fa3.x), s2.y, h2.y), 0.f));
        fa3.y = pack2(fmaxf(fmaf(bflo(fa3.y), s2.z, h2.z), 0.f),
                      fmaxf(fmaf(bfhi(fa3.y), s2.w, h2.w), 0.f));
        fa3.z = pack2(fmaxf(fmaf(bflo(fa3.z), s3.x, h3.x), 0.f),
                      fmaxf(fmaf(bfhi(fa3.z), s3.y, h3.y), 0.f));
        fa3.w = pack2(fmaxf(fmaf(bflo(fa3.w), s3.z, h3.z), 0.f),
                      fmaxf(fmaf(bfhi(fa3.w), s3.w, h3.w), 0.f));
    }
    uint4 fa[4] = {fa0, fa1, fa2, fa3};

    f32x4 acc0 = {0.f, 0.f, 0.f, 0.f}, acc1 = acc0, acc2 = acc0, acc3 = acc0;
#pragma unroll
    for (int c = 0; c < 4; ++c) {
        uint4 b0 = wb[(0 * 16 + col) * 16 + c * 4 + q];
        uint4 b1 = wb[(1 * 16 + col) * 16 + c * 4 + q];
        uint4 b2 = wb[(2 * 16 + col) * 16 + c * 4 + q];
        uint4 b3 = wb[(3 * 16 + col) * 16 + c * 4 + q];
        bf16x8 a = *(const bf16x8*)&fa[c];
        acc0 = __builtin_amdgcn_mfma_f32_16x16x32_bf16(a, *(const bf16x8*)&b0, acc0, 0, 0, 0);
        acc1 = __builtin_amdgcn_mfma_f32_16x16x32_bf16(a, *(const bf16x8*)&b1, acc1, 0, 0, 0);
        acc2 = __builtin_amdgcn_mfma_f32_16x16x32_bf16(a, *(const bf16x8*)&b2, acc2, 0, 0, 0);
        acc3 = __builtin_amdgcn_mfma_f32_16x16x32_bf16(a, *(const bf16x8*)&b3, acc3, 0, 0, 0);
    }

    float bb0 = bias[col], bb1 = bias[16 + col], bb2 = bias[32 + col], bb3 = bias[48 + col];
    float sj0 = 0.f, sj1 = 0.f, sj2 = 0.f, sj3 = 0.f;
    float qj0 = 0.f, qj1 = 0.f, qj2 = 0.f, qj3 = 0.f;
#pragma unroll
    for (int r = 0; r < 4; ++r) {
        int go = base + w * 16 + q * 4 + r;
        float o0 = acc0[r] + bb0, o1 = acc1[r] + bb1;
        float o2 = acc2[r] + bb2, o3 = acc3[r] + bb3;
        float ssv = o0 * o0 + o1 * o1 + o2 * o2 + o3 * o3;
        ssv += __shfl_xor(ssv, 1, 64);
        ssv += __shfl_xor(ssv, 2, 64);
        ssv += __shfl_xor(ssv, 4, 64);
        ssv += __shfl_xor(ssv, 8, 64);
        float inv = 1.0f / fmaxf(sqrtf(ssv), 1e-12f);
        o0 *= inv; o1 *= inv; o2 *= inv; o3 *= inv;
        if (go < NN) {
            outbf[go * 64 + col]      = bf16_of(o0);
            outbf[go * 64 + 16 + col] = bf16_of(o1);
            outbf[go * 64 + 32 + col] = bf16_of(o2);
            outbf[go * 64 + 48 + col] = bf16_of(o3);
            sj0 += o0; sj1 += o1; sj2 += o2; sj3 += o3;
            qj0 += o0 * o0; qj1 += o1 * o1; qj2 += o2 * o2; qj3 += o3 * o3;
        }
    }
#pragma unroll
    for (int m = 16; m <= 32; m <<= 1) {
        sj0 += __shfl_xor(sj0, m, 64); sj1 += __shfl_xor(sj1, m, 64);
        sj2 += __shfl_xor(sj2, m, 64); sj3 += __shfl_xor(sj3, m, 64);
        qj0 += __shfl_xor(qj0, m, 64); qj1 += __shfl_xor(qj1, m, 64);
        qj2 += __shfl_xor(qj2, m, 64); qj3 += __shfl_xor(qj3, m, 64);
    }
    __syncthreads();
    if (q == 0) {
        atomicAdd(&sblk[col], sj0);      atomicAdd(&qblk[col], qj0);
        atomicAdd(&sblk[16 + col], sj1); atomicAdd(&qblk[16 + col], qj1);
        atomicAdd(&sblk[32 + col], sj2); atomicAdd(&qblk[32 + col], qj2);
        atomicAdd(&sblk[48 + col], sj3); atomicAdd(&qblk[48 + col], qj3);
    }
    __syncthreads();
    if (tid < 128)
        atomicAdd(&p64[(blockIdx.x & 63) * 128 + tid],
                  (tid < 64) ? sblk[tid] : qblk[tid - 64]);
    __threadfence();
    __syncthreads();
    if (tid == 0) {
        int old = atomicAdd(counter, 1);
        lastflag = (old == (int)gridDim.x - 1) ? 1 : 0;
    }
    __syncthreads();
    if (lastflag) {
        __threadfence();     // acquire: all blocks' p64 adds visible
        int idx = tid & 127, half = tid >> 7;
        float a = 0.f;
#pragma unroll
        for (int r = half; r < 64; r += 2)
            a += p64[r * 128 + idx];
        red2[tid] = a;
        __syncthreads();
        if (tid < 128) fin[tid] = red2[tid] + red2[tid + 128];
        __syncthreads();
        if (tid < 64) {
            float mu = fin[tid] / (float)NN;
            float var = fmaxf(fin[64 + tid] / (float)NN - mu * mu, 0.f);
            float scv = g[tid] / sqrtf(var + 1e-5f);
            scale[tid] = scv;
            shift[tid] = be[tid] - mu * scv;
        }
    }
}

// ---------------- layer-3 projection (reads bf16 h2raw) ----------------
__global__ __launch_bounds__(256)
void k_project(const unsigned short* __restrict__ h,     // h2 raw bf16 (N,64)
               const float* __restrict__ sc, const float* __restrict__ sh,
               const float* __restrict__ Wl, const float* __restrict__ Wr,
               const float* __restrict__ bias,
               float* __restrict__ zl, float* __restrict__ zr) {
    __shared__ float Alds[64 * 128];
    __shared__ float Wlds[64 * 32];
    const int tid = threadIdx.x;
    const int base = blockIdx.x * 128;

#pragma unroll
    for (int i = 0; i < 8; ++i) {
        int idx = i * 256 + tid;
        int f = idx & 31, k = idx >> 5;
        float v = 0.0f;
        if (f < 16) { if (f < 10) v = Wl[f * 64 + k]; }
        else        { if (f - 16 < 10) v = Wr[(f - 16) * 64 + k]; }
        Wlds[k * 32 + f] = v;
    }
    {
        const uint4* h4 = (const uint4*)h;
        const float4* sc4p = (const float4*)sc;
        const float4* sh4p = (const float4*)sh;
#pragma unroll
        for (int i = 0; i < 4; ++i) {
            int idx = i * 256 + tid;
            int node = idx & 127, cb = idx >> 7;
            int gn = base + node; if (gn > NN - 1) gn = NN - 1;
            uint4 u = h4[gn * 8 + cb];
            float4 sA = sc4p[cb * 2], sB = sc4p[cb * 2 + 1];
            float4 hA = sh4p[cb * 2], hB = sh4p[cb * 2 + 1];
            int k0 = cb * 8;
            Alds[(k0 + 0) * 128 + node] = fmaxf(fmaf(bflo(u.x), sA.x, hA.x), 0.f);
            Alds[(k0 + 1) * 128 + node] = fmaxf(fmaf(bfhi(u.x), sA.y, hA.y), 0.f);
            Alds[(k0 + 2) * 128 + node] = fmaxf(fmaf(bflo(u.y), sA.z, hA.z), 0.f);
            Alds[(k0 + 3) * 128 + node] = fmaxf(fmaf(bfhi(u.y), sA.w, hA.w), 0.f);
            Alds[(k0 + 4) * 128 + node] = fmaxf(fmaf(bflo(u.z), sB.x, hB.x), 0.f);
            Alds[(k0 + 5) * 128 + node] = fmaxf(fmaf(bfhi(u.z), sB.y, hB.y), 0.f);
            Alds[(k0 + 6) * 128 + node] = fmaxf(fmaf(bflo(u.w), sB.z, hB.z), 0.f);
            Alds[(k0 + 7) * 128 + node] = fmaxf(fmaf(bfhi(u.w), sB.w, hB.w), 0.f);
        }
    }
    __syncthreads();

    const int fg = tid & 7;
    const int ng = tid >> 3;

    float acc[4][4] = {};
#pragma unroll 4
    for (int k = 0; k < 64; ++k) {
        const float4 a = *(const float4*)(Alds + k * 128 + (ng << 2));
        const float4 w = *(const float4*)(Wlds + k * 32 + (fg << 2));
        const float av[4] = {a.x, a.y, a.z, a.w};
        const float wv[4] = {w.x, w.y, w.z, w.w};
#pragma unroll
        for (int i = 0; i < 4; ++i)
#pragma unroll
            for (int j = 0; j < 4; ++j)
                acc[i][j] = fmaf(av[i], wv[j], acc[i][j]);
    }

    if (fg == 3 || fg == 7) return;
    float4* dst = (fg < 4) ? (float4*)zl : (float4*)zr;
    int fq = (fg < 4) ? fg : fg - 4;
    float bx = 0.f, by = 0.f, bz = 0.f, bw = 0.f;
    if (fg >= 4) {
        int f0 = fq * 4;
        bx = (f0 + 0 < 10) ? bias[f0 + 0] : 0.f;
        by = (f0 + 1 < 10) ? bias[f0 + 1] : 0.f;
        bz = (f0 + 2 < 10) ? bias[f0 + 2] : 0.f;
        bw = (f0 + 3 < 10) ? bias[f0 + 3] : 0.f;
    }
#pragma unroll
    for (int i = 0; i < 4; ++i) {
        int gn = base + (ng << 2) + i;
        if (gn < NN)
            dst[gn * 3 + fq] = make_float4(acc[i][0] + bx, acc[i][1] + by,
                                           acc[i][2] + bz, acc[i][3] + bw);
    }
}

// ---------------- layer-3 aggregation (unroll-4 for MLP) ----------------
__global__ __launch_bounds__(256)
void k_agg10(const int* __restrict__ rs, const int* __restrict__ esrc,
             const float* __restrict__ zl, const float* __restrict__ zr,
             float* __restrict__ out) {
    int gid = blockIdx.x * 256 + threadIdx.x;
    unsigned node = (unsigned)gid / 3u;
    int j = gid - (int)node * 3;
    if (node >= NN) return;
    int s0 = rs[node], s1 = rs[node + 1];
    const float4* zl4 = (const float4*)zl;
    float4 acc = make_float4(0.f, 0.f, 0.f, 0.f);
    int p = s0;
    for (; p + 3 < s1; p += 4) {
        float4 v0 = zl4[esrc[p] * 3 + j];
        float4 v1 = zl4[esrc[p + 1] * 3 + j];
        float4 v2 = zl4[esrc[p + 2] * 3 + j];
        float4 v3 = zl4[esrc[p + 3] * 3 + j];
        acc.x += (v0.x + v1.x) + (v2.x + v3.x);
        acc.y += (v0.y + v1.y) + (v2.y + v3.y);
        acc.z += (v0.z + v1.z) + (v2.z + v3.z);
        acc.w += (v0.w + v1.w) + (v2.w + v3.w);
    }
    for (; p < s1; ++p) {
        float4 v = zl4[esrc[p] * 3 + j];
        acc.x += v.x; acc.y += v.y; acc.z += v.z; acc.w += v.w;
    }
    int cnt = s1 - s0; if (cnt < 1) cnt = 1;
    float inv = 1.0f / (float)cnt;
    float4 r = ((const float4*)zr)[node * 3 + j];
    r.x = fmaf(acc.x, inv, r.x); r.y = fmaf(acc.y, inv, r.y);
    r.z = fmaf(acc.z, inv, r.z); r.w = fmaf(acc.w, inv, r.w);
    float2* o2 = (float2*)(out + (size_t)node * 10);
    if (j < 2) {
        o2[j * 2 + 0] = make_float2(r.x, r.y);
        o2[j * 2 + 1] = make_float2(r.z, r.w);
    } else {
        o2[4] = make_float2(r.x, r.y);
    }
}

// ---------------- launch ----------------

extern "C" void kernel_launch(void* const* d_in, const int* in_sizes, int n_in,
                              void* d_out, int out_size, void* d_ws, size_t ws_size,
                              hipStream_t stream) {
    const float* x   = (const float*)d_in[0];
    const int*   ei  = (const int*)d_in[1];
    const float* Wl1 = (const float*)d_in[2];
    const float* Wr1 = (const float*)d_in[3];
    const float* b1  = (const float*)d_in[4];
    const float* g1  = (const float*)d_in[5];
    const float* be1 = (const float*)d_in[6];
    const float* Wl2 = (const float*)d_in[7];
    const float* Wr2 = (const float*)d_in[8];
    const float* b2  = (const float*)d_in[9];
    const float* g2  = (const float*)d_in[10];
    const float* be2 = (const float*)d_in[11];
    const float* Wl3 = (const float*)d_in[12];
    const float* Wr3 = (const float*)d_in[13];
    const float* b3  = (const float*)d_in[14];
    float* out = (float*)d_out;

    char* w = (char*)d_ws;
    auto alloc = [&](size_t bytes) -> void* {
        void* p = (void*)w;
        w += (bytes + 255) & ~(size_t)255;
        return p;
    };
    int*   ccount = (int*)alloc(256 * 4);
    int*   cbase  = (int*)alloc(256 * 4);
    int*   gcur   = (int*)alloc(256 * 4);
    int*   counters = (int*)alloc(256 * 4);
    int*   rs     = (int*)alloc((size_t)(NN + 1) * 4);
    int*   esrc   = (int*)alloc((size_t)EE * 4);
    float* scratch= (float*)alloc((size_t)NN * 64 * 4);   // pairs / zl / zr
    unsigned short* xbf    = (unsigned short*)alloc((size_t)NN * 64 * 2);  // x bf16, then h2raw bf16
    unsigned short* h1bf   = (unsigned short*)alloc((size_t)NN * 64 * 2);
    unsigned short* meanbf = (unsigned short*)alloc((size_t)NN * 64 * 2);
    unsigned short* wbf1   = (unsigned short*)alloc(8192 * 2);
    unsigned short* wbf2   = (unsigned short*)alloc(8192 * 2);
    float* p64a   = (float*)alloc(8192 * 4);  // BN slot-groups, layer 1
    float* p64b   = (float*)alloc(8192 * 4);  // BN slot-groups, layer 2
    float* scsh   = (float*)alloc(256 * 4);   // scale1, shift1, scale2, shift2
    int*   pairs  = (int*)scratch;
    float* zl     = scratch;
    float* zr     = scratch + (size_t)NN * 12;

    // fused conversion + packing + scratch zeroing (ccount, p64a/b, counters)
    k_tobfW<<<6251, 256, 0, stream>>>((const float4*)x, (ushort4*)xbf,
                                      Wl1, Wr1, Wl2, Wr2, wbf1, wbf2,
                                      ccount, p64a, p64b, counters);
    k_ccount<<<NCH, 256, 0, stream>>>(ei, ccount);
    k_cscan<<<1, 256, 0, stream>>>(ccount, cbase, gcur);
    k_coarse<<<NCH, 256, 0, stream>>>(ei, gcur, pairs);
    k_fine<<<NBKT, 512, 0, stream>>>(cbase, pairs, rs, esrc);

    const int aggBlocks  = (NN * 64) / 256;      // 25000 (1 wave / node)
    const int sageBlocks = (NN + 63) / 64;       // 1563
    const int projBlocks = (NN + 127) / 128;     // 782
    const int a10Blocks  = (NN * 3 + 255) / 256; // 1172

    // layer 1: mean(xbf) -> meanbf; MFMA -> h1bf; BN1 stats fused (last block)
    k_aggbf<<<aggBlocks, 256, 0, stream>>>(xbf, rs, esrc, meanbf, nullptr, nullptr);
    k_sagemfma<<<sageBlocks, 256, 0, stream>>>(meanbf, xbf, wbf1, b1, h1bf,
                                               p64a, counters + 0, g1, be1,
                                               scsh + 0, scsh + 64, nullptr, nullptr);

    // layer 2: mean(relu(bn1(h1bf))) -> meanbf; MFMA (BN fused on A2) -> h2raw bf16 (reuses xbf)
    k_aggbf<<<aggBlocks, 256, 0, stream>>>(h1bf, rs, esrc, meanbf, scsh + 0, scsh + 64);
    k_sagemfma<<<sageBlocks, 256, 0, stream>>>(meanbf, h1bf, wbf2, b2, xbf,
                                               p64b, counters + 1, g2, be2,
                                               scsh + 128, scsh + 192, scsh + 0, scsh + 64);

    // layer 3: project (BN2+ReLU fused, bf16 input) then 10-dim aggregate
    k_project<<<projBlocks, 256, 0, stream>>>(xbf, scsh + 128, scsh + 192,
                                              Wl3, Wr3, b3, zl, zr);
    k_agg10<<<a10Blocks, 256, 0, stream>>>(rs, esrc, zl, zr, out);
}

// Round 14
// 334.521 us; speedup vs baseline: 1.9608x; 1.9608x over previous
//
#include <hip/hip_runtime.h>
#include <hip/hip_bf16.h>

#define NN 100000
#define EE 1600000
#define BSZ 512    // dst-nodes per coarse bucket
#define NBKT 196   // ceil(NN/BSZ)
#define CHUNK 8192 // edges per coarse chunk
#define NCH 196    // ceil(EE/CHUNK)

typedef short bf16x8 __attribute__((ext_vector_type(8)));
typedef float f32x4 __attribute__((ext_vector_type(4)));

// ---------------- bf16 helpers ----------------
__device__ inline unsigned short bf16_of(float f) {
    __hip_bfloat16 h = __float2bfloat16(f);   // RNE
    return *reinterpret_cast<unsigned short*>(&h);
}
__device__ inline unsigned pack2(float a, float b) {
    return (unsigned)bf16_of(a) | ((unsigned)bf16_of(b) << 16);
}
__device__ inline float bflo(unsigned u) { return __uint_as_float(u << 16); }
__device__ inline float bfhi(unsigned u) { return __uint_as_float(u & 0xffff0000u); }

// ---------------- CSR build ----------------

__global__ __launch_bounds__(256)
void k_ccount(const int* __restrict__ ei, int* __restrict__ ccount) {
    __shared__ int hist[NBKT];
    int tid = threadIdx.x;
    int e0 = blockIdx.x * CHUNK;
    int e1 = e0 + CHUNK; if (e1 > EE) e1 = EE;
    for (int i = tid; i < NBKT; i += 256) hist[i] = 0;
    __syncthreads();
    for (int e = e0 + tid; e < e1; e += 256)
        atomicAdd(&hist[ei[EE + e] >> 9], 1);
    __syncthreads();
    for (int i = tid; i < NBKT; i += 256)
        if (hist[i]) atomicAdd(&ccount[i], hist[i]);
}

__global__ void k_cscan(const int* __restrict__ ccount, int* __restrict__ cbase,
                        int* __restrict__ gcur) {
    __shared__ int s[256];
    int tid = threadIdx.x;
    int v = (tid < NBKT) ? ccount[tid] : 0;
    s[tid] = v;
    __syncthreads();
    for (int off = 1; off < 256; off <<= 1) {
        int t = (tid >= off) ? s[tid - off] : 0;
        __syncthreads();
        if (tid >= off) s[tid] += t;
        __syncthreads();
    }
    if (tid < NBKT) {
        int excl = s[tid] - v;
        cbase[tid] = excl;
        gcur[tid] = excl;
    }
    if (tid == NBKT - 1) cbase[NBKT] = s[tid];
}

// pairs packed: (src << 9) | (dst & 511)
__global__ __launch_bounds__(256)
void k_coarse(const int* __restrict__ ei, int* __restrict__ gcur, int* __restrict__ pairs) {
    __shared__ int hist[NBKT];
    __shared__ int base[NBKT];
    __shared__ int curs[NBKT];
    int tid = threadIdx.x;
    int e0 = blockIdx.x * CHUNK;
    int e1 = e0 + CHUNK; if (e1 > EE) e1 = EE;
    for (int i = tid; i < NBKT; i += 256) hist[i] = 0;
    __syncthreads();
    for (int e = e0 + tid; e < e1; e += 256)
        atomicAdd(&hist[ei[EE + e] >> 9], 1);
    __syncthreads();
    for (int i = tid; i < NBKT; i += 256) {
        base[i] = atomicAdd(&gcur[i], hist[i]);
        curs[i] = 0;
    }
    __syncthreads();
    for (int e = e0 + tid; e < e1; e += 256) {
        int src = ei[e];
        int dst = ei[EE + e];
        int b = dst >> 9;
        int off = atomicAdd(&curs[b], 1);
        pairs[base[b] + off] = (src << 9) | (dst & 511);
    }
}

__global__ __launch_bounds__(512)
void k_fine(const int* __restrict__ cbase, const int* __restrict__ pairs,
            int* __restrict__ rs, int* __restrict__ esrc) {
    __shared__ int deg[BSZ];
    __shared__ int s[BSZ];
    int b = blockIdx.x;
    int n0 = b * BSZ;
    int nlocal = NN - n0; if (nlocal > BSZ) nlocal = BSZ;
    int tid = threadIdx.x;
    deg[tid] = 0;
    __syncthreads();
    int e0 = cbase[b], e1 = cbase[b + 1];
    for (int e = e0 + tid; e < e1; e += 512)
        atomicAdd(&deg[pairs[e] & 511], 1);
    __syncthreads();
    int v = deg[tid];
    s[tid] = v;
    __syncthreads();
    for (int off = 1; off < 512; off <<= 1) {
        int t = (tid >= off) ? s[tid - off] : 0;
        __syncthreads();
        if (tid >= off) s[tid] += t;
        __syncthreads();
    }
    int excl = s[tid] - v;
    if (tid < nlocal) rs[n0 + tid] = e0 + excl;
    if (b == NBKT - 1 && tid == 0) rs[NN] = EE;
    deg[tid] = e0 + excl;
    __syncthreads();
    for (int e = e0 + tid; e < e1; e += 512) {
        int pk = pairs[e];
        int pos = atomicAdd(&deg[pk & 511], 1);
        esrc[pos] = pk >> 9;
    }
}

// ---------------- fused: x->bf16 + W packing + ccount zeroing ----------------
__global__ __launch_bounds__(256)
void k_tobfW(const float4* __restrict__ src, ushort4* __restrict__ dst,
             const float* __restrict__ Wl1, const float* __restrict__ Wr1,
             const float* __restrict__ Wl2, const float* __restrict__ Wr2,
             unsigned short* __restrict__ w1, unsigned short* __restrict__ w2,
             int* __restrict__ ccount) {
    int b = blockIdx.x, tid = threadIdx.x;
    if (b < 6250) {
        int i = b * 256 + tid;
        if (i < NN * 16) {
            float4 v = src[i];
            dst[i] = make_ushort4(bf16_of(v.x), bf16_of(v.y), bf16_of(v.z), bf16_of(v.w));
        }
    } else {
        for (int i = tid; i < 8192; i += 256) {
            int n = i >> 7, k = i & 127;
            float v1 = (k < 64) ? Wl1[n * 64 + k] : Wr1[n * 64 + (k - 64)];
            w1[i] = bf16_of(v1);
            float v2 = (k < 64) ? Wl2[n * 64 + k] : Wr2[n * 64 + (k - 64)];
            w2[i] = bf16_of(v2);
        }
        if (tid < NBKT) ccount[tid] = 0;
    }
}

// ---------------- aggregation (64-dim) over bf16 table -> bf16 mean ----------------
__global__ __launch_bounds__(256, 8)
void k_aggbf(const unsigned short* __restrict__ xbf, const int* __restrict__ rs,
             const int* __restrict__ esrc, unsigned short* __restrict__ meanbf,
             const float* __restrict__ sc, const float* __restrict__ sh) {
    int gid = blockIdx.x * 256 + threadIdx.x;
    int node = gid >> 6;
    if (node >= NN) return;
    int lane = threadIdx.x & 63;
    int c = lane & 7;         // feature octet
    int slot = lane >> 3;     // neighbor slot 0..7
    int s0 = rs[node], s1 = rs[node + 1];
    const uint4* xb = (const uint4*)xbf;
    float a0 = 0.f, a1 = 0.f, a2 = 0.f, a3 = 0.f, a4 = 0.f, a5 = 0.f, a6 = 0.f, a7 = 0.f;
    if (sc) {
        float4 scl = ((const float4*)sc)[2 * c], sch = ((const float4*)sc)[2 * c + 1];
        float4 shl = ((const float4*)sh)[2 * c], shh = ((const float4*)sh)[2 * c + 1];
        int p = s0 + slot;
        for (; p + 8 < s1; p += 16) {
            uint4 va = xb[esrc[p] * 8 + c];
            uint4 vb = xb[esrc[p + 8] * 8 + c];
            a0 += fmaxf(fmaf(bflo(va.x), scl.x, shl.x), 0.f);
            a1 += fmaxf(fmaf(bfhi(va.x), scl.y, shl.y), 0.f);
            a2 += fmaxf(fmaf(bflo(va.y), scl.z, shl.z), 0.f);
            a3 += fmaxf(fmaf(bfhi(va.y), scl.w, shl.w), 0.f);
            a4 += fmaxf(fmaf(bflo(va.z), sch.x, shh.x), 0.f);
            a5 += fmaxf(fmaf(bfhi(va.z), sch.y, shh.y), 0.f);
            a6 += fmaxf(fmaf(bflo(va.w), sch.z, shh.z), 0.f);
            a7 += fmaxf(fmaf(bfhi(va.w), sch.w, shh.w), 0.f);
            a0 += fmaxf(fmaf(bflo(vb.x), scl.x, shl.x), 0.f);
            a1 += fmaxf(fmaf(bfhi(vb.x), scl.y, shl.y), 0.f);
            a2 += fmaxf(fmaf(bflo(vb.y), scl.z, shl.z), 0.f);
            a3 += fmaxf(fmaf(bfhi(vb.y), scl.w, shl.w), 0.f);
            a4 += fmaxf(fmaf(bflo(vb.z), sch.x, shh.x), 0.f);
            a5 += fmaxf(fmaf(bfhi(vb.z), sch.y, shh.y), 0.f);
            a6 += fmaxf(fmaf(bflo(vb.w), sch.z, shh.z), 0.f);
            a7 += fmaxf(fmaf(bfhi(vb.w), sch.w, shh.w), 0.f);
        }
        if (p < s1) {
            uint4 va = xb[esrc[p] * 8 + c];
            a0 += fmaxf(fmaf(bflo(va.x), scl.x, shl.x), 0.f);
            a1 += fmaxf(fmaf(bfhi(va.x), scl.y, shl.y), 0.f);
            a2 += fmaxf(fmaf(bflo(va.y), scl.z, shl.z), 0.f);
            a3 += fmaxf(fmaf(bfhi(va.y), scl.w, shl.w), 0.f);
            a4 += fmaxf(fmaf(bflo(va.z), sch.x, shh.x), 0.f);
            a5 += fmaxf(fmaf(bfhi(va.z), sch.y, shh.y), 0.f);
            a6 += fmaxf(fmaf(bflo(va.w), sch.z, shh.z), 0.f);
            a7 += fmaxf(fmaf(bfhi(va.w), sch.w, shh.w), 0.f);
        }
    } else {
        int p = s0 + slot;
        for (; p + 8 < s1; p += 16) {
            uint4 va = xb[esrc[p] * 8 + c];
            uint4 vb = xb[esrc[p + 8] * 8 + c];
            a0 += bflo(va.x) + bflo(vb.x); a1 += bfhi(va.x) + bfhi(vb.x);
            a2 += bflo(va.y) + bflo(vb.y); a3 += bfhi(va.y) + bfhi(vb.y);
            a4 += bflo(va.z) + bflo(vb.z); a5 += bfhi(va.z) + bfhi(vb.z);
            a6 += bflo(va.w) + bflo(vb.w); a7 += bfhi(va.w) + bfhi(vb.w);
        }
        if (p < s1) {
            uint4 va = xb[esrc[p] * 8 + c];
            a0 += bflo(va.x); a1 += bfhi(va.x);
            a2 += bflo(va.y); a3 += bfhi(va.y);
            a4 += bflo(va.z); a5 += bfhi(va.z);
            a6 += bflo(va.w); a7 += bfhi(va.w);
        }
    }
#pragma unroll
    for (int m = 8; m <= 32; m <<= 1) {
        a0 += __shfl_xor(a0, m, 64); a1 += __shfl_xor(a1, m, 64);
        a2 += __shfl_xor(a2, m, 64); a3 += __shfl_xor(a3, m, 64);
        a4 += __shfl_xor(a4, m, 64); a5 += __shfl_xor(a5, m, 64);
        a6 += __shfl_xor(a6, m, 64); a7 += __shfl_xor(a7, m, 64);
    }
    if (slot == 0) {
        int cnt = s1 - s0; if (cnt < 1) cnt = 1;
        float inv = 1.0f / (float)cnt;
        uint4 o;
        o.x = pack2(a0 * inv, a1 * inv);
        o.y = pack2(a2 * inv, a3 * inv);
        o.z = pack2(a4 * inv, a5 * inv);
        o.w = pack2(a6 * inv, a7 * inv);
        ((uint4*)meanbf)[node * 8 + c] = o;
    }
}

// ---------------- SAGE layer: LDS-free bf16 MFMA GEMM + bias + L2-norm + BN stats ----------------
// BN stats: per-block partials to a PRIVATE slot (no global atomics, no fences
// — R13's last-block fence pattern cost 200us/dispatch in stalls).
__global__ __launch_bounds__(256, 4)
void k_sagemfma(const unsigned short* __restrict__ meanbf,  // (N,64) bf16
                const unsigned short* __restrict__ a2bf,    // (N,64) bf16
                const unsigned short* __restrict__ Wbf,     // (64,128) bf16 packed
                const float* __restrict__ bias,
                unsigned short* __restrict__ outbf,         // (N,64) bf16
                float* __restrict__ partials,               // (nblk,128): sum|ssq
                const float* __restrict__ sc, const float* __restrict__ sh) {
    __shared__ float sblk[64];
    __shared__ float qblk[64];
    const int tid = threadIdx.x;
    const int base = blockIdx.x * 64;
    const int col = tid & 15;
    const int q   = (tid >> 4) & 3;
    const int w   = tid >> 6;

    if (tid < 64) { sblk[tid] = 0.f; qblk[tid] = 0.f; }

    int gn = base + w * 16 + col; if (gn > NN - 1) gn = NN - 1;
    const uint4* mb = (const uint4*)meanbf;
    const uint4* ab = (const uint4*)a2bf;
    const uint4* wb = (const uint4*)Wbf;

    uint4 fa0 = mb[gn * 8 + q];
    uint4 fa1 = mb[gn * 8 + 4 + q];
    uint4 fa2 = ab[gn * 8 + q];
    uint4 fa3 = ab[gn * 8 + 4 + q];
    if (sc) {
        float4 s0 = ((const float4*)sc)[q * 2],     s1 = ((const float4*)sc)[q * 2 + 1];
        float4 h0 = ((const float4*)sh)[q * 2],     h1 = ((const float4*)sh)[q * 2 + 1];
        float4 s2 = ((const float4*)sc)[8 + q * 2], s3 = ((const float4*)sc)[8 + q * 2 + 1];
        float4 h2 = ((const float4*)sh)[8 + q * 2], h3 = ((const float4*)sh)[8 + q * 2 + 1];
        fa2.x = pack2(fmaxf(fmaf(bflo(fa2.x), s0.x, h0.x), 0.f),
                      fmaxf(fmaf(bfhi(fa2.x), s0.y, h0.y), 0.f));
        fa2.y = pack2(fmaxf(fmaf(bflo(fa2.y), s0.z, h0.z), 0.f),
                      fmaxf(fmaf(bfhi(fa2.y), s0.w, h0.w), 0.f));
        fa2.z = pack2(fmaxf(fmaf(bflo(fa2.z), s1.x, h1.x), 0.f),
                      fmaxf(fmaf(bfhi(fa2.z), s1.y, h1.y), 0.f));
        fa2.w = pack2(fmaxf(fmaf(bflo(fa2.w), s1.z, h1.z), 0.f),
                      fmaxf(fmaf(bfhi(fa2.w), s1.w, h1.w), 0.f));
        fa3.x = pack2(fmaxf(fmaf(bflo(fa3.x), s2.x, h2.x), 0.f),
                      fmaxf(fmaf(bfhi(fa3.x), s2.y, h2.y), 0.f));
        fa3.y = pack2(fmaxf(fmaf(bflo(fa3.y), s2.z, h2.z), 0.f),
                      fmaxf(fmaf(bfhi(fa3.y), s2.w, h2.w), 0.f));
        fa3.z = pack2(fmaxf(fmaf(bflo(fa3.z), s3.x, h3.x), 0.f),
                      fmaxf(fmaf(bfhi(fa3.z), s3.y, h3.y), 0.f));
        fa3.w = pack2(fmaxf(fmaf(bflo(fa3.w), s3.z, h3.z), 0.f),
                      fmaxf(fmaf(bfhi(fa3.w), s3.w, h3.w), 0.f));
    }
    uint4 fa[4] = {fa0, fa1, fa2, fa3};

    f32x4 acc0 = {0.f, 0.f, 0.f, 0.f}, acc1 = acc0, acc2 = acc0, acc3 = acc0;
#pragma unroll
    for (int c = 0; c < 4; ++c) {
        uint4 b0 = wb[(0 * 16 + col) * 16 + c * 4 + q];
        uint4 b1 = wb[(1 * 16 + col) * 16 + c * 4 + q];
        uint4 b2 = wb[(2 * 16 + col) * 16 + c * 4 + q];
        uint4 b3 = wb[(3 * 16 + col) * 16 + c * 4 + q];
        bf16x8 a = *(const bf16x8*)&fa[c];
        acc0 = __builtin_amdgcn_mfma_f32_16x16x32_bf16(a, *(const bf16x8*)&b0, acc0, 0, 0, 0);
        acc1 = __builtin_amdgcn_mfma_f32_16x16x32_bf16(a, *(const bf16x8*)&b1, acc1, 0, 0, 0);
        acc2 = __builtin_amdgcn_mfma_f32_16x16x32_bf16(a, *(const bf16x8*)&b2, acc2, 0, 0, 0);
        acc3 = __builtin_amdgcn_mfma_f32_16x16x32_bf16(a, *(const bf16x8*)&b3, acc3, 0, 0, 0);
    }

    float bb0 = bias[col], bb1 = bias[16 + col], bb2 = bias[32 + col], bb3 = bias[48 + col];
    float sj0 = 0.f, sj1 = 0.f, sj2 = 0.f, sj3 = 0.f;
    float qj0 = 0.f, qj1 = 0.f, qj2 = 0.f, qj3 = 0.f;
#pragma unroll
    for (int r = 0; r < 4; ++r) {
        int go = base + w * 16 + q * 4 + r;
        float o0 = acc0[r] + bb0, o1 = acc1[r] + bb1;
        float o2 = acc2[r] + bb2, o3 = acc3[r] + bb3;
        float ssv = o0 * o0 + o1 * o1 + o2 * o2 + o3 * o3;
        ssv += __shfl_xor(ssv, 1, 64);
        ssv += __shfl_xor(ssv, 2, 64);
        ssv += __shfl_xor(ssv, 4, 64);
        ssv += __shfl_xor(ssv, 8, 64);
        float inv = 1.0f / fmaxf(sqrtf(ssv), 1e-12f);
        o0 *= inv; o1 *= inv; o2 *= inv; o3 *= inv;
        if (go < NN) {
            outbf[go * 64 + col]      = bf16_of(o0);
            outbf[go * 64 + 16 + col] = bf16_of(o1);
            outbf[go * 64 + 32 + col] = bf16_of(o2);
            outbf[go * 64 + 48 + col] = bf16_of(o3);
            sj0 += o0; sj1 += o1; sj2 += o2; sj3 += o3;
            qj0 += o0 * o0; qj1 += o1 * o1; qj2 += o2 * o2; qj3 += o3 * o3;
        }
    }
#pragma unroll
    for (int m = 16; m <= 32; m <<= 1) {
        sj0 += __shfl_xor(sj0, m, 64); sj1 += __shfl_xor(sj1, m, 64);
        sj2 += __shfl_xor(sj2, m, 64); sj3 += __shfl_xor(sj3, m, 64);
        qj0 += __shfl_xor(qj0, m, 64); qj1 += __shfl_xor(qj1, m, 64);
        qj2 += __shfl_xor(qj2, m, 64); qj3 += __shfl_xor(qj3, m, 64);
    }
    __syncthreads();
    if (q == 0) {
        atomicAdd(&sblk[col], sj0);      atomicAdd(&qblk[col], qj0);
        atomicAdd(&sblk[16 + col], sj1); atomicAdd(&qblk[16 + col], qj1);
        atomicAdd(&sblk[32 + col], sj2); atomicAdd(&qblk[32 + col], qj2);
        atomicAdd(&sblk[48 + col], sj3); atomicAdd(&qblk[48 + col], qj3);
    }
    __syncthreads();
    if (tid < 128)
        partials[blockIdx.x * 128 + tid] = (tid < 64) ? sblk[tid] : qblk[tid - 64];
}

// ---------------- BN reduce stage 1: (nblk,128) -> (32,128), 32 blocks ----------------
__global__ __launch_bounds__(256)
void k_bnred(const float* __restrict__ partials, int nblk, float* __restrict__ red) {
    __shared__ float s[256];
    int tid = threadIdx.x;
    int idx = tid & 127, half = tid >> 7;
    float a0 = 0.f, a1 = 0.f, a2 = 0.f, a3 = 0.f;
    int r = blockIdx.x * 2 + half;       // residue mod 64
    for (; r + 192 < nblk; r += 256) {
        a0 += partials[r * 128 + idx];
        a1 += partials[(r + 64) * 128 + idx];
        a2 += partials[(r + 128) * 128 + idx];
        a3 += partials[(r + 192) * 128 + idx];
    }
    for (; r < nblk; r += 64) a0 += partials[r * 128 + idx];
    s[tid] = (a0 + a1) + (a2 + a3);
    __syncthreads();
    if (tid < 128) red[blockIdx.x * 128 + tid] = s[tid] + s[tid + 128];
}

// ---------------- BN finalize ----------------
__global__ void k_bnfin(const float* __restrict__ red,
                        const float* __restrict__ g, const float* __restrict__ be,
                        float* __restrict__ scale, float* __restrict__ shift) {
    __shared__ float s[256];
    int tid = threadIdx.x;
    int idx = tid & 127, half = tid >> 7;
    float a = 0.f;
#pragma unroll
    for (int r = half; r < 32; r += 2)
        a += red[r * 128 + idx];
    s[tid] = a;
    __syncthreads();
    if (tid < 128) s[tid] += s[tid + 128];
    __syncthreads();
    if (tid < 64) {
        float mu = s[tid] / (float)NN;
        float var = s[64 + tid] / (float)NN - mu * mu;
        var = fmaxf(var, 0.0f);
        float sc = g[tid] / sqrtf(var + 1e-5f);
        scale[tid] = sc;
        shift[tid] = be[tid] - mu * sc;
    }
}

// ---------------- layer-3 projection (reads bf16 h2raw) ----------------
__global__ __launch_bounds__(256)
void k_project(const unsigned short* __restrict__ h,     // h2 raw bf16 (N,64)
               const float* __restrict__ sc, const float* __restrict__ sh,
               const float* __restrict__ Wl, const float* __restrict__ Wr,
               const float* __restrict__ bias,
               float* __restrict__ zl, float* __restrict__ zr) {
    __shared__ float Alds[64 * 128];
    __shared__ float Wlds[64 * 32];
    const int tid = threadIdx.x;
    const int base = blockIdx.x * 128;

#pragma unroll
    for (int i = 0; i < 8; ++i) {
        int idx = i * 256 + tid;
        int f = idx & 31, k = idx >> 5;
        float v = 0.0f;
        if (f < 16) { if (f < 10) v = Wl[f * 64 + k]; }
        else        { if (f - 16 < 10) v = Wr[(f - 16) * 64 + k]; }
        Wlds[k * 32 + f] = v;
    }
    {
        const uint4* h4 = (const uint4*)h;
        const float4* sc4p = (const float4*)sc;
        const float4* sh4p = (const float4*)sh;
#pragma unroll
        for (int i = 0; i < 4; ++i) {
            int idx = i * 256 + tid;
            int node = idx & 127, cb = idx >> 7;
            int gn = base + node; if (gn > NN - 1) gn = NN - 1;
            uint4 u = h4[gn * 8 + cb];
            float4 sA = sc4p[cb * 2], sB = sc4p[cb * 2 + 1];
            float4 hA = sh4p[cb * 2], hB = sh4p[cb * 2 + 1];
            int k0 = cb * 8;
            Alds[(k0 + 0) * 128 + node] = fmaxf(fmaf(bflo(u.x), sA.x, hA.x), 0.f);
            Alds[(k0 + 1) * 128 + node] = fmaxf(fmaf(bfhi(u.x), sA.y, hA.y), 0.f);
            Alds[(k0 + 2) * 128 + node] = fmaxf(fmaf(bflo(u.y), sA.z, hA.z), 0.f);
            Alds[(k0 + 3) * 128 + node] = fmaxf(fmaf(bfhi(u.y), sA.w, hA.w), 0.f);
            Alds[(k0 + 4) * 128 + node] = fmaxf(fmaf(bflo(u.z), sB.x, hB.x), 0.f);
            Alds[(k0 + 5) * 128 + node] = fmaxf(fmaf(bfhi(u.z), sB.y, hB.y), 0.f);
            Alds[(k0 + 6) * 128 + node] = fmaxf(fmaf(bflo(u.w), sB.z, hB.z), 0.f);
            Alds[(k0 + 7) * 128 + node] = fmaxf(fmaf(bfhi(u.w), sB.w, hB.w), 0.f);
        }
    }
    __syncthreads();

    const int fg = tid & 7;
    const int ng = tid >> 3;

    float acc[4][4] = {};
#pragma unroll 4
    for (int k = 0; k < 64; ++k) {
        const float4 a = *(const float4*)(Alds + k * 128 + (ng << 2));
        const float4 w = *(const float4*)(Wlds + k * 32 + (fg << 2));
        const float av[4] = {a.x, a.y, a.z, a.w};
        const float wv[4] = {w.x, w.y, w.z, w.w};
#pragma unroll
        for (int i = 0; i < 4; ++i)
#pragma unroll
            for (int j = 0; j < 4; ++j)
                acc[i][j] = fmaf(av[i], wv[j], acc[i][j]);
    }

    if (fg == 3 || fg == 7) return;
    float4* dst = (fg < 4) ? (float4*)zl : (float4*)zr;
    int fq = (fg < 4) ? fg : fg - 4;
    float bx = 0.f, by = 0.f, bz = 0.f, bw = 0.f;
    if (fg >= 4) {
        int f0 = fq * 4;
        bx = (f0 + 0 < 10) ? bias[f0 + 0] : 0.f;
        by = (f0 + 1 < 10) ? bias[f0 + 1] : 0.f;
        bz = (f0 + 2 < 10) ? bias[f0 + 2] : 0.f;
        bw = (f0 + 3 < 10) ? bias[f0 + 3] : 0.f;
    }
#pragma unroll
    for (int i = 0; i < 4; ++i) {
        int gn = base + (ng << 2) + i;
        if (gn < NN)
            dst[gn * 3 + fq] = make_float4(acc[i][0] + bx, acc[i][1] + by,
                                           acc[i][2] + bz, acc[i][3] + bw);
    }
}

// ---------------- layer-3 aggregation (unroll-4 for MLP) ----------------
__global__ __launch_bounds__(256)
void k_agg10(const int* __restrict__ rs, const int* __restrict__ esrc,
             const float* __restrict__ zl, const float* __restrict__ zr,
             float* __restrict__ out) {
    int gid = blockIdx.x * 256 + threadIdx.x;
    unsigned node = (unsigned)gid / 3u;
    int j = gid - (int)node * 3;
    if (node >= NN) return;
    int s0 = rs[node], s1 = rs[node + 1];
    const float4* zl4 = (const float4*)zl;
    float4 acc = make_float4(0.f, 0.f, 0.f, 0.f);
    int p = s0;
    for (; p + 3 < s1; p += 4) {
        float4 v0 = zl4[esrc[p] * 3 + j];
        float4 v1 = zl4[esrc[p + 1] * 3 + j];
        float4 v2 = zl4[esrc[p + 2] * 3 + j];
        float4 v3 = zl4[esrc[p + 3] * 3 + j];
        acc.x += (v0.x + v1.x) + (v2.x + v3.x);
        acc.y += (v0.y + v1.y) + (v2.y + v3.y);
        acc.z += (v0.z + v1.z) + (v2.z + v3.z);
        acc.w += (v0.w + v1.w) + (v2.w + v3.w);
    }
    for (; p < s1; ++p) {
        float4 v = zl4[esrc[p] * 3 + j];
        acc.x += v.x; acc.y += v.y; acc.z += v.z; acc.w += v.w;
    }
    int cnt = s1 - s0; if (cnt < 1) cnt = 1;
    float inv = 1.0f / (float)cnt;
    float4 r = ((const float4*)zr)[node * 3 + j];
    r.x = fmaf(acc.x, inv, r.x); r.y = fmaf(acc.y, inv, r.y);
    r.z = fmaf(acc.z, inv, r.z); r.w = fmaf(acc.w, inv, r.w);
    float2* o2 = (float2*)(out + (size_t)node * 10);
    if (j < 2) {
        o2[j * 2 + 0] = make_float2(r.x, r.y);
        o2[j * 2 + 1] = make_float2(r.z, r.w);
    } else {
        o2[4] = make_float2(r.x, r.y);
    }
}

// ---------------- launch ----------------

extern "C" void kernel_launch(void* const* d_in, const int* in_sizes, int n_in,
                              void* d_out, int out_size, void* d_ws, size_t ws_size,
                              hipStream_t stream) {
    const float* x   = (const float*)d_in[0];
    const int*   ei  = (const int*)d_in[1];
    const float* Wl1 = (const float*)d_in[2];
    const float* Wr1 = (const float*)d_in[3];
    const float* b1  = (const float*)d_in[4];
    const float* g1  = (const float*)d_in[5];
    const float* be1 = (const float*)d_in[6];
    const float* Wl2 = (const float*)d_in[7];
    const float* Wr2 = (const float*)d_in[8];
    const float* b2  = (const float*)d_in[9];
    const float* g2  = (const float*)d_in[10];
    const float* be2 = (const float*)d_in[11];
    const float* Wl3 = (const float*)d_in[12];
    const float* Wr3 = (const float*)d_in[13];
    const float* b3  = (const float*)d_in[14];
    float* out = (float*)d_out;

    char* w = (char*)d_ws;
    auto alloc = [&](size_t bytes) -> void* {
        void* p = (void*)w;
        w += (bytes + 255) & ~(size_t)255;
        return p;
    };
    int*   ccount = (int*)alloc(256 * 4);
    int*   cbase  = (int*)alloc(256 * 4);
    int*   gcur   = (int*)alloc(256 * 4);
    int*   rs     = (int*)alloc((size_t)(NN + 1) * 4);
    int*   esrc   = (int*)alloc((size_t)EE * 4);
    float* scratch= (float*)alloc((size_t)NN * 64 * 4);   // pairs / zl / zr
    unsigned short* xbf    = (unsigned short*)alloc((size_t)NN * 64 * 2);  // x bf16, then h2raw bf16
    unsigned short* h1bf   = (unsigned short*)alloc((size_t)NN * 64 * 2);
    unsigned short* meanbf = (unsigned short*)alloc((size_t)NN * 64 * 2);
    unsigned short* wbf1   = (unsigned short*)alloc(8192 * 2);
    unsigned short* wbf2   = (unsigned short*)alloc(8192 * 2);
    float* partials = (float*)alloc((size_t)1563 * 128 * 4);  // per-block BN partials
    float* red    = (float*)alloc(32 * 128 * 4);              // stage-1 reduction
    float* scsh   = (float*)alloc(256 * 4);   // scale1, shift1, scale2, shift2
    int*   pairs  = (int*)scratch;
    float* zl     = scratch;
    float* zr     = scratch + (size_t)NN * 12;

    // fused conversion + packing + ccount zeroing
    k_tobfW<<<6251, 256, 0, stream>>>((const float4*)x, (ushort4*)xbf,
                                      Wl1, Wr1, Wl2, Wr2, wbf1, wbf2, ccount);
    k_ccount<<<NCH, 256, 0, stream>>>(ei, ccount);
    k_cscan<<<1, 256, 0, stream>>>(ccount, cbase, gcur);
    k_coarse<<<NCH, 256, 0, stream>>>(ei, gcur, pairs);
    k_fine<<<NBKT, 512, 0, stream>>>(cbase, pairs, rs, esrc);

    const int aggBlocks  = (NN * 64) / 256;      // 25000 (1 wave / node)
    const int sageBlocks = (NN + 63) / 64;       // 1563
    const int projBlocks = (NN + 127) / 128;     // 782
    const int a10Blocks  = (NN * 3 + 255) / 256; // 1172

    // layer 1: mean(xbf) -> meanbf; MFMA -> h1bf
    k_aggbf<<<aggBlocks, 256, 0, stream>>>(xbf, rs, esrc, meanbf, nullptr, nullptr);
    k_sagemfma<<<sageBlocks, 256, 0, stream>>>(meanbf, xbf, wbf1, b1, h1bf,
                                               partials, nullptr, nullptr);
    k_bnred<<<32, 256, 0, stream>>>(partials, sageBlocks, red);
    k_bnfin<<<1, 256, 0, stream>>>(red, g1, be1, scsh + 0, scsh + 64);

    // layer 2: mean(relu(bn1(h1bf))) -> meanbf; MFMA (BN fused on A2) -> h2raw bf16 (reuses xbf)
    k_aggbf<<<aggBlocks, 256, 0, stream>>>(h1bf, rs, esrc, meanbf, scsh + 0, scsh + 64);
    k_sagemfma<<<sageBlocks, 256, 0, stream>>>(meanbf, h1bf, wbf2, b2, xbf,
                                               partials, scsh + 0, scsh + 64);
    k_bnred<<<32, 256, 0, stream>>>(partials, sageBlocks, red);
    k_bnfin<<<1, 256, 0, stream>>>(red, g2, be2, scsh + 128, scsh + 192);

    // layer 3: project (BN2+ReLU fused, bf16 input) then 10-dim aggregate
    k_project<<<projBlocks, 256, 0, stream>>>(xbf, scsh + 128, scsh + 192,
                                              Wl3, Wr3, b3, zl, zr);
    k_agg10<<<a10Blocks, 256, 0, stream>>>(rs, esrc, zl, zr, out);
}